// Round 1
// baseline (182.111 us; speedup 1.0000x reference)
//
#include <hip/hip_runtime.h>
#include <hip/hip_bf16.h>

#define N_NODES 8192
#define E_EDGES 16384
#define S_SEG   16
#define EXT     64
#define P_PATHS 2048
#define ROW     (S_SEG * EXT)   // 1024 floats per row
#define TE      4               // edges per block

typedef __bf16 bf16x8 __attribute__((ext_vector_type(8)));
typedef float  f32x4  __attribute__((ext_vector_type(4)));
typedef int    int4v  __attribute__((ext_vector_type(4)));

// pack two fp32 -> packed bf16x2 (RNE), as int
__device__ __forceinline__ int pack_bf16(float a, float b) {
#if __has_builtin(__builtin_amdgcn_cvt_pk_bf16_f32)
    auto r = __builtin_amdgcn_cvt_pk_bf16_f32(a, b);
    return __builtin_bit_cast(int, r);
#else
    unsigned ua = __float_as_uint(a), ub = __float_as_uint(b);
    ua = (ua + 0x7fffu + ((ua >> 16) & 1u)) >> 16;
    ub = (ub + 0x7fffu + ((ub >> 16) & 1u)) & 0xffff0000u;
    return (int)(ua | ub);
#endif
}

// ---------------------------------------------------------------------------
// Kernel 1: build dense bf16 Cmat[k][i*16+j] from sparse paths (duplicates add)
// ---------------------------------------------------------------------------
__global__ void build_C(const int* __restrict__ pidx,
                        const float* __restrict__ pcoef,
                        unsigned short* __restrict__ Cmat) {
    __shared__ float sC[S_SEG * S_SEG * S_SEG];   // 4096 floats
    const int tid = threadIdx.x;
    for (int i = tid; i < S_SEG * S_SEG * S_SEG; i += 256) sC[i] = 0.f;
    __syncthreads();
    for (int p = tid; p < P_PATHS; p += 256) {
        int i = pidx[3 * p + 0];
        int j = pidx[3 * p + 1];
        int k = pidx[3 * p + 2];
        atomicAdd(&sC[(k * S_SEG + i) * S_SEG + j], pcoef[p]);
    }
    __syncthreads();
    for (int idx = tid; idx < S_SEG * S_SEG * S_SEG; idx += 256) {
        unsigned u = __float_as_uint(sC[idx]);
        u = (u + 0x7fffu + ((u >> 16) & 1u)) >> 16;
        Cmat[idx] = (unsigned short)u;
    }
}

// ---------------------------------------------------------------------------
// Kernel 2: per-edge GEMM  out_e(16x64) = Cmat(16x256) @ W(256x64),
//           W[(i,j),c] = x[idx_in[e]][i][c] * y[e][j][c], scatter-add to out.
// One wave owns a 16-channel slice; 8x mfma_f32_16x16x32_bf16 per edge.
// ---------------------------------------------------------------------------
__global__ __launch_bounds__(256) void seg_poly(
        const float* __restrict__ x, const float* __restrict__ y,
        const int* __restrict__ idx_in, const int* __restrict__ idx_out,
        const unsigned short* __restrict__ Cmat, float* __restrict__ out) {
    __shared__ __attribute__((aligned(16))) float sx[TE][ROW];
    __shared__ __attribute__((aligned(16))) float sy[TE][ROW];

    const int tid  = threadIdx.x;
    const int lane = tid & 63;
    const int wv   = tid >> 6;                 // wave id 0..3 -> channel chunk
    const int quad = lane >> 4;                // 0..3
    const int c    = wv * 16 + (lane & 15);    // channel 0..63

    // A fragments (constant across edges): a[kk] elem jr = Cmat[m][kk*32+quad*8+jr]
    int4v afrag[8];
    {
        const int m = lane & 15;
        const unsigned short* base = Cmat + m * 256 + quad * 8;
#pragma unroll
        for (int kk = 0; kk < 8; ++kk)
            afrag[kk] = *(const int4v*)(base + kk * 32);
    }

    const int e0 = blockIdx.x * TE;

    // Stage TE edges: gathered x row + y row, coalesced float4 (1 float4/thread/row)
#pragma unroll
    for (int t = 0; t < TE; ++t) {
        const int e = e0 + t;
        const float4* xs = (const float4*)(x + (size_t)idx_in[e] * ROW);
        const float4* ys = (const float4*)(y + (size_t)e * ROW);
        ((float4*)sx[t])[tid] = xs[tid];
        ((float4*)sy[t])[tid] = ys[tid];
    }
    __syncthreads();

#pragma unroll
    for (int t = 0; t < TE; ++t) {
        const int e = e0 + t;

        // per-lane y values: j_seg = (quad&1)*8 + jr  (reused across all 8 K-steps)
        const int jb = (quad & 1) * 8;
        float yv[8];
#pragma unroll
        for (int jr = 0; jr < 8; ++jr) yv[jr] = sy[t][(jb + jr) * EXT + c];

        const int ih = quad >> 1;  // i_seg parity within each K-step
        f32x4 acc = {0.f, 0.f, 0.f, 0.f};
#pragma unroll
        for (int kk = 0; kk < 8; ++kk) {
            const float xc = sx[t][(kk * 2 + ih) * EXT + c];
            int4v bi;
            bi[0] = pack_bf16(xc * yv[0], xc * yv[1]);
            bi[1] = pack_bf16(xc * yv[2], xc * yv[3]);
            bi[2] = pack_bf16(xc * yv[4], xc * yv[5]);
            bi[3] = pack_bf16(xc * yv[6], xc * yv[7]);
            acc = __builtin_amdgcn_mfma_f32_16x16x32_bf16(
                __builtin_bit_cast(bf16x8, afrag[kk]),
                __builtin_bit_cast(bf16x8, bi), acc, 0, 0, 0);
        }

        // D layout: lane -> col = lane&15 (channel c), row k_out = quad*4 + r
        float* ob = out + (size_t)idx_out[e] * ROW;
#pragma unroll
        for (int r = 0; r < 4; ++r)
            atomicAdd(ob + (quad * 4 + r) * EXT + c, acc[r]);
    }
}

extern "C" void kernel_launch(void* const* d_in, const int* in_sizes, int n_in,
                              void* d_out, int out_size, void* d_ws, size_t ws_size,
                              hipStream_t stream) {
    const float* x        = (const float*)d_in[0];
    const float* y        = (const float*)d_in[1];
    const int*   idx_in   = (const int*)d_in[2];
    const int*   idx_out  = (const int*)d_in[3];
    const int*   pidx     = (const int*)d_in[4];
    const float* pcoef    = (const float*)d_in[5];
    float* out            = (float*)d_out;
    unsigned short* Cmat  = (unsigned short*)d_ws;   // 4096 bf16 = 8 KB

    // d_out is re-poisoned before every launch; we accumulate with atomics -> zero it.
    hipMemsetAsync(d_out, 0, (size_t)out_size * sizeof(float), stream);

    build_C<<<1, 256, 0, stream>>>(pidx, pcoef, Cmat);
    seg_poly<<<E_EDGES / TE, 256, 0, stream>>>(x, y, idx_in, idx_out, Cmat, out);
}

// Round 2
// 169.279 us; speedup vs baseline: 1.0758x; 1.0758x over previous
//
#include <hip/hip_runtime.h>
#include <hip/hip_bf16.h>

#define N_NODES 8192
#define E_EDGES 16384
#define S_SEG   16
#define EXT     64
#define P_PATHS 2048
#define ROW     (S_SEG * EXT)   // 1024 floats per row

typedef _Float16 f16x8  __attribute__((ext_vector_type(8)));
typedef _Float16 half2v __attribute__((ext_vector_type(2)));
typedef float    f32x4  __attribute__((ext_vector_type(4)));

// ---- workspace layout (bytes) ----
// Cmat   f16[4096]      @ 0        (8 KB)
// hist   int[8192]      @ 8192
// cursor int[8192]      @ 40960
// rows   int[8193]      @ 73728
// elist  int[16384]     @ 106512   (16-aligned)
#define WS_CMAT  0
#define WS_HIST  8192
#define WS_CURS  40960
#define WS_ROWS  73728
#define WS_ELIST 106512

// ---------------------------------------------------------------------------
// prep: blocks 0..31 zero hist; block 32 builds dense f16 Cmat[k][i*16+j]
// ---------------------------------------------------------------------------
__global__ void prep(const int* __restrict__ pidx, const float* __restrict__ pcoef,
                     _Float16* __restrict__ Cmat, int* __restrict__ hist) {
    const int tid = threadIdx.x;
    if (blockIdx.x < 32) {
        hist[blockIdx.x * 256 + tid] = 0;
        return;
    }
    __shared__ float sC[S_SEG * S_SEG * S_SEG];
    for (int i = tid; i < 4096; i += 256) sC[i] = 0.f;
    __syncthreads();
    for (int p = tid; p < P_PATHS; p += 256) {
        int i = pidx[3 * p + 0];
        int j = pidx[3 * p + 1];
        int k = pidx[3 * p + 2];
        atomicAdd(&sC[(k * S_SEG + i) * S_SEG + j], pcoef[p]);
    }
    __syncthreads();
    for (int i = tid; i < 4096; i += 256) Cmat[i] = (_Float16)sC[i];
}

// ---------------------------------------------------------------------------
// hist: count edges per output node
// ---------------------------------------------------------------------------
__global__ void hist_k(const int* __restrict__ idx_out, int* __restrict__ hist) {
    const int e = blockIdx.x * 256 + threadIdx.x;
    atomicAdd(&hist[idx_out[e]], 1);
}

// ---------------------------------------------------------------------------
// scan: exclusive prefix over hist[8192] -> rows[8193], copy to cursor
// one block, 256 threads, 32 nodes/thread
// ---------------------------------------------------------------------------
__global__ __launch_bounds__(256) void scan_k(const int* __restrict__ hist,
                                              int* __restrict__ rows,
                                              int* __restrict__ cursor) {
    __shared__ int part[256];
    const int t = threadIdx.x;
    const int base = t * 32;
    int loc[32];
    int s = 0;
#pragma unroll
    for (int i = 0; i < 32; ++i) { loc[i] = s; s += hist[base + i]; }
    part[t] = s;
    __syncthreads();
    for (int off = 1; off < 256; off <<= 1) {
        int v = part[t];
        int u = (t >= off) ? part[t - off] : 0;
        __syncthreads();
        part[t] = v + u;
        __syncthreads();
    }
    const int excl = (t == 0) ? 0 : part[t - 1];
#pragma unroll
    for (int i = 0; i < 32; ++i) {
        int v = excl + loc[i];
        rows[base + i] = v;
        cursor[base + i] = v;
    }
    if (t == 255) rows[N_NODES] = part[255];
}

// ---------------------------------------------------------------------------
// scatter: edge id -> sorted-by-idx_out edge list
// ---------------------------------------------------------------------------
__global__ void scatter_k(const int* __restrict__ idx_out, int* __restrict__ cursor,
                          int* __restrict__ elist) {
    const int e = blockIdx.x * 256 + threadIdx.x;
    const int pos = atomicAdd(&cursor[idx_out[e]], 1);
    elist[pos] = e;
}

// ---------------------------------------------------------------------------
// main: one block per output node. For each incident edge:
//   out_n(16x64) += Cmat(16x256) @ W(256x64),  W[(i,j),c] = x[idx_in[e]][i][c]*y[e][j][c]
// fp16 inputs, fp32 MFMA accumulate in registers; single clean store, no atomics.
// ---------------------------------------------------------------------------
__global__ __launch_bounds__(256) void seg_poly_node(
        const float* __restrict__ x, const float* __restrict__ y,
        const int* __restrict__ idx_in, const _Float16* __restrict__ Cmat,
        const int* __restrict__ rows, const int* __restrict__ elist,
        float* __restrict__ out) {
    __shared__ __attribute__((aligned(16))) _Float16 sxh[ROW];  // [i*64+c]
    __shared__ __attribute__((aligned(16))) half2v  syp[512];   // [jp*64+c] = (y[2jp][c], y[2jp+1][c])

    const int tid  = threadIdx.x;
    const int lane = tid & 63;
    const int wv   = tid >> 6;
    const int quad = lane >> 4;
    const int c    = wv * 16 + (lane & 15);      // channel 0..63
    const int n    = blockIdx.x;

    const int beg = rows[n];
    const int end = rows[n + 1];

    // A fragments (constant): afrag[kk][jr] = Cmat[m][kk*32 + quad*8 + jr], m = lane&15
    f16x8 afrag[8];
    {
        const _Float16* basep = Cmat + (lane & 15) * 256 + quad * 8;
#pragma unroll
        for (int kk = 0; kk < 8; ++kk)
            afrag[kk] = *(const f16x8*)(basep + kk * 32);
    }

    f32x4 acc = {0.f, 0.f, 0.f, 0.f};
    const int jb2 = (quad & 1) * 4;   // ypk row base (pairs)
    const int ih  = quad >> 1;        // i parity within K-step

    for (int p = beg; p < end; ++p) {
        const int e  = elist[p];
        const int xr = idx_in[e];

        // stage x row -> f16 LDS (4 floats/thread, coalesced)
        {
            const float4 xv = *(const float4*)(x + (size_t)xr * ROW + tid * 4);
            half2v* sxp = (half2v*)sxh;
            sxp[tid * 2]     = half2v{(_Float16)xv.x, (_Float16)xv.y};
            sxp[tid * 2 + 1] = half2v{(_Float16)xv.z, (_Float16)xv.w};
        }
        // stage y row -> paired f16 LDS (threads 0..127, 2 float4 each)
        if (tid < 128) {
            const int jp = tid >> 4;
            const int cq = (tid & 15) * 4;
            const float* yb = y + (size_t)e * ROW;
            const float4 ya = *(const float4*)(yb + (2 * jp) * EXT + cq);
            const float4 yc = *(const float4*)(yb + (2 * jp + 1) * EXT + cq);
            syp[jp * 64 + cq + 0] = half2v{(_Float16)ya.x, (_Float16)yc.x};
            syp[jp * 64 + cq + 1] = half2v{(_Float16)ya.y, (_Float16)yc.y};
            syp[jp * 64 + cq + 2] = half2v{(_Float16)ya.z, (_Float16)yc.z};
            syp[jp * 64 + cq + 3] = half2v{(_Float16)ya.w, (_Float16)yc.w};
        }
        __syncthreads();

        half2v ypk[4];
#pragma unroll
        for (int r = 0; r < 4; ++r) ypk[r] = syp[(jb2 + r) * 64 + c];

#pragma unroll
        for (int kk = 0; kk < 8; ++kk) {
            const _Float16 xh = sxh[(2 * kk + ih) * EXT + c];
            const half2v hx = {xh, xh};
            const half2v b0 = hx * ypk[0];
            const half2v b1 = hx * ypk[1];
            const half2v b2 = hx * ypk[2];
            const half2v b3 = hx * ypk[3];
            const f16x8 bfrag = {b0[0], b0[1], b1[0], b1[1], b2[0], b2[1], b3[0], b3[1]};
            acc = __builtin_amdgcn_mfma_f32_16x16x32_f16(afrag[kk], bfrag, acc, 0, 0, 0);
        }
        __syncthreads();   // protect LDS restage of next edge
    }

    // single clean store; zero-degree nodes write zeros (acc stayed 0)
    float* ob = out + (size_t)n * ROW;
#pragma unroll
    for (int r = 0; r < 4; ++r)
        ob[(quad * 4 + r) * EXT + c] = acc[r];
}

extern "C" void kernel_launch(void* const* d_in, const int* in_sizes, int n_in,
                              void* d_out, int out_size, void* d_ws, size_t ws_size,
                              hipStream_t stream) {
    const float* x       = (const float*)d_in[0];
    const float* y       = (const float*)d_in[1];
    const int*   idx_in  = (const int*)d_in[2];
    const int*   idx_out = (const int*)d_in[3];
    const int*   pidx    = (const int*)d_in[4];
    const float* pcoef   = (const float*)d_in[5];
    float* out           = (float*)d_out;

    char* ws = (char*)d_ws;
    _Float16* Cmat = (_Float16*)(ws + WS_CMAT);
    int* hist      = (int*)(ws + WS_HIST);
    int* cursor    = (int*)(ws + WS_CURS);
    int* rows      = (int*)(ws + WS_ROWS);
    int* elist     = (int*)(ws + WS_ELIST);

    prep<<<33, 256, 0, stream>>>(pidx, pcoef, Cmat, hist);
    hist_k<<<E_EDGES / 256, 256, 0, stream>>>(idx_out, hist);
    scan_k<<<1, 256, 0, stream>>>(hist, rows, cursor);
    scatter_k<<<E_EDGES / 256, 256, 0, stream>>>(idx_out, cursor, elist);
    seg_poly_node<<<N_NODES, 256, 0, stream>>>(x, y, idx_in, Cmat, rows, elist, out);
}

// Round 3
// 165.611 us; speedup vs baseline: 1.0996x; 1.0222x over previous
//
#include <hip/hip_runtime.h>
#include <hip/hip_bf16.h>

#define N_NODES 8192
#define E_EDGES 16384
#define S_SEG   16
#define EXT     64
#define P_PATHS 2048
#define ROW     (S_SEG * EXT)   // 1024 floats per row

typedef _Float16 f16x8  __attribute__((ext_vector_type(8)));
typedef _Float16 f16x4  __attribute__((ext_vector_type(4)));
typedef _Float16 half2v __attribute__((ext_vector_type(2)));
typedef float    f32x4  __attribute__((ext_vector_type(4)));

// ---- workspace layout (bytes) ----
#define WS_CMAT  0        // f16[4096]  (8 KB)
#define WS_HIST  8192     // int[8192]
#define WS_CURS  40960    // int[8192]
#define WS_ROWS  73728    // int[8193]
#define WS_ELIST 106512   // int[16384]

// ---------------------------------------------------------------------------
// prep: blocks 0..31 zero hist; block 32 builds dense f16 Cmat[k][i*16+j]
// ---------------------------------------------------------------------------
__global__ void prep(const int* __restrict__ pidx, const float* __restrict__ pcoef,
                     _Float16* __restrict__ Cmat, int* __restrict__ hist) {
    const int tid = threadIdx.x;
    if (blockIdx.x < 32) {
        hist[blockIdx.x * 256 + tid] = 0;
        return;
    }
    __shared__ float sC[S_SEG * S_SEG * S_SEG];
    for (int i = tid; i < 4096; i += 256) sC[i] = 0.f;
    __syncthreads();
    for (int p = tid; p < P_PATHS; p += 256) {
        int i = pidx[3 * p + 0];
        int j = pidx[3 * p + 1];
        int k = pidx[3 * p + 2];
        atomicAdd(&sC[(k * S_SEG + i) * S_SEG + j], pcoef[p]);
    }
    __syncthreads();
    for (int i = tid; i < 4096; i += 256) Cmat[i] = (_Float16)sC[i];
}

__global__ void hist_k(const int* __restrict__ idx_out, int* __restrict__ hist) {
    const int e = blockIdx.x * 256 + threadIdx.x;
    atomicAdd(&hist[idx_out[e]], 1);
}

__global__ __launch_bounds__(256) void scan_k(const int* __restrict__ hist,
                                              int* __restrict__ rows,
                                              int* __restrict__ cursor) {
    __shared__ int part[256];
    const int t = threadIdx.x;
    const int base = t * 32;
    int loc[32];
    int s = 0;
#pragma unroll
    for (int i = 0; i < 32; ++i) { loc[i] = s; s += hist[base + i]; }
    part[t] = s;
    __syncthreads();
    for (int off = 1; off < 256; off <<= 1) {
        int v = part[t];
        int u = (t >= off) ? part[t - off] : 0;
        __syncthreads();
        part[t] = v + u;
        __syncthreads();
    }
    const int excl = (t == 0) ? 0 : part[t - 1];
#pragma unroll
    for (int i = 0; i < 32; ++i) {
        int v = excl + loc[i];
        rows[base + i] = v;
        cursor[base + i] = v;
    }
    if (t == 255) rows[N_NODES] = part[255];
}

__global__ void scatter_k(const int* __restrict__ idx_out, int* __restrict__ cursor,
                          int* __restrict__ elist) {
    const int e = blockIdx.x * 256 + threadIdx.x;
    const int pos = atomicAdd(&cursor[idx_out[e]], 1);
    elist[pos] = e;
}

// ---------------------------------------------------------------------------
// main: one WAVE per output node, private LDS slice, zero barriers.
// Per edge: out_n(16x64) += Cmat(16x256) @ W(256x64),
//           W[(i,j),c] = x[idx_in[e]][i][c] * y[e][j][c]
// 4 col-tiles x 8 K-steps of mfma_f32_16x16x32_f16, fp32 accum in regs.
// ---------------------------------------------------------------------------
__global__ __launch_bounds__(256) void seg_poly_wave(
        const float* __restrict__ x, const float* __restrict__ y,
        const int* __restrict__ idx_in, const _Float16* __restrict__ Cmat,
        const int* __restrict__ rows, const int* __restrict__ elist,
        float* __restrict__ out) {
    // per-wave private slices: 2KB x (f16[1024]) + 2KB y-pairs (half2[512])
    __shared__ __attribute__((aligned(16))) _Float16 sx_all[4][ROW];
    __shared__ __attribute__((aligned(16))) half2v   sy_all[4][512];

    const int tid  = threadIdx.x;
    const int lane = tid & 63;
    const int wv   = tid >> 6;
    _Float16* sxh = sx_all[wv];
    half2v*   syp = sy_all[wv];

    const int n = blockIdx.x * 4 + wv;
    const int beg = rows[n];
    const int end = rows[n + 1];

    const int quad = lane >> 4;     // 0..3
    const int m    = lane & 15;     // row (A) / col-within-tile (B,D)
    const int jb2  = (quad & 1) * 4; // y-pair row base
    const int ih   = quad >> 1;      // i parity within K-step

    // A fragments (constant): afrag[kk][jr] = Cmat[m][kk*32 + quad*8 + jr]
    f16x8 afrag[8];
    {
        const _Float16* basep = Cmat + m * 256 + quad * 8;
#pragma unroll
        for (int kk = 0; kk < 8; ++kk)
            afrag[kk] = *(const f16x8*)(basep + kk * 32);
    }

    f32x4 acc[4];
#pragma unroll
    for (int ct = 0; ct < 4; ++ct) acc[ct] = f32x4{0.f, 0.f, 0.f, 0.f};

    for (int p = beg; p < end; ++p) {
        const int e  = elist[p];
        const int xr = idx_in[e];

        // ---- stage x row -> f16 LDS slice (4x float4 per lane, coalesced) ----
        {
            const float* xb = x + (size_t)xr * ROW;
#pragma unroll
            for (int k4 = 0; k4 < 4; ++k4) {
                const float4 v = *(const float4*)(xb + k4 * 256 + lane * 4);
                f16x4 h = {(_Float16)v.x, (_Float16)v.y, (_Float16)v.z, (_Float16)v.w};
                *(f16x4*)(sxh + k4 * 256 + lane * 4) = h;
            }
        }
        // ---- stage y row -> paired f16 LDS: syp[jp*64+c] = (y[2jp][c], y[2jp+1][c]) ----
        {
            const int jp = lane >> 3;          // 0..7
            const int cq = (lane & 7) * 8;     // 8 cols per lane
            const float* yb = y + (size_t)e * ROW;
            const float4 a0 = *(const float4*)(yb + (2 * jp)     * EXT + cq);
            const float4 a1 = *(const float4*)(yb + (2 * jp)     * EXT + cq + 4);
            const float4 b0 = *(const float4*)(yb + (2 * jp + 1) * EXT + cq);
            const float4 b1 = *(const float4*)(yb + (2 * jp + 1) * EXT + cq + 4);
            f16x8 p0 = {(_Float16)a0.x, (_Float16)b0.x, (_Float16)a0.y, (_Float16)b0.y,
                        (_Float16)a0.z, (_Float16)b0.z, (_Float16)a0.w, (_Float16)b0.w};
            f16x8 p1 = {(_Float16)a1.x, (_Float16)b1.x, (_Float16)a1.y, (_Float16)b1.y,
                        (_Float16)a1.z, (_Float16)b1.z, (_Float16)a1.w, (_Float16)b1.w};
            *(f16x8*)(syp + jp * 64 + cq)     = p0;
            *(f16x8*)(syp + jp * 64 + cq + 4) = p1;
        }
        // no __syncthreads: LDS slice is wave-private, lgkmcnt orders within wave

        // ---- compute: 4 col-tiles x 8 K-steps ----
#pragma unroll
        for (int ct = 0; ct < 4; ++ct) {
            const int c = ct * 16 + m;
            half2v ypk[4];
#pragma unroll
            for (int r = 0; r < 4; ++r) ypk[r] = syp[(jb2 + r) * 64 + c];
#pragma unroll
            for (int kk = 0; kk < 8; ++kk) {
                const _Float16 xh = sxh[(2 * kk + ih) * EXT + c];
                const half2v hx = {xh, xh};
                const half2v b0 = hx * ypk[0];
                const half2v b1 = hx * ypk[1];
                const half2v b2 = hx * ypk[2];
                const half2v b3 = hx * ypk[3];
                const f16x8 bfrag = {b0[0], b0[1], b1[0], b1[1],
                                     b2[0], b2[1], b3[0], b3[1]};
                acc[ct] = __builtin_amdgcn_mfma_f32_16x16x32_f16(
                              afrag[kk], bfrag, acc[ct], 0, 0, 0);
            }
        }
    }

    // single clean store; zero-degree nodes write zeros
    float* ob = out + (size_t)n * ROW;
#pragma unroll
    for (int ct = 0; ct < 4; ++ct)
#pragma unroll
        for (int r = 0; r < 4; ++r)
            ob[(quad * 4 + r) * EXT + ct * 16 + m] = acc[ct][r];
}

extern "C" void kernel_launch(void* const* d_in, const int* in_sizes, int n_in,
                              void* d_out, int out_size, void* d_ws, size_t ws_size,
                              hipStream_t stream) {
    const float* x       = (const float*)d_in[0];
    const float* y       = (const float*)d_in[1];
    const int*   idx_in  = (const int*)d_in[2];
    const int*   idx_out = (const int*)d_in[3];
    const int*   pidx    = (const int*)d_in[4];
    const float* pcoef   = (const float*)d_in[5];
    float* out           = (float*)d_out;

    char* ws = (char*)d_ws;
    _Float16* Cmat = (_Float16*)(ws + WS_CMAT);
    int* hist      = (int*)(ws + WS_HIST);
    int* cursor    = (int*)(ws + WS_CURS);
    int* rows      = (int*)(ws + WS_ROWS);
    int* elist     = (int*)(ws + WS_ELIST);

    prep<<<33, 256, 0, stream>>>(pidx, pcoef, Cmat, hist);
    hist_k<<<E_EDGES / 256, 256, 0, stream>>>(idx_out, hist);
    scan_k<<<1, 256, 0, stream>>>(hist, rows, cursor);
    scatter_k<<<E_EDGES / 256, 256, 0, stream>>>(idx_out, cursor, elist);
    seg_poly_wave<<<N_NODES / 4, 256, 0, stream>>>(x, y, idx_in, Cmat, rows, elist, out);
}

// Round 4
// 162.181 us; speedup vs baseline: 1.1229x; 1.0211x over previous
//
#include <hip/hip_runtime.h>
#include <hip/hip_bf16.h>

#define N_NODES 8192
#define E_EDGES 16384
#define S_SEG   16
#define EXT     64
#define P_PATHS 2048
#define ROW     1024            // S_SEG*EXT floats per row
#define L_SLOTS 8               // edge slots per wave
#define NWAVES  (E_EDGES / L_SLOTS)   // 2048
#define NBLK    (NWAVES / 4)          // 512 blocks x 4 waves

typedef _Float16 f16x8  __attribute__((ext_vector_type(8)));
typedef _Float16 f16x4  __attribute__((ext_vector_type(4)));
typedef _Float16 half2v __attribute__((ext_vector_type(2)));
typedef float    f32x4  __attribute__((ext_vector_type(4)));

// ---- workspace layout (bytes) ----
#define WS_CMAT  0        // f16[4096]   8 KB
#define WS_HIST  8192     // int[8192]
#define WS_CURS  40960    // int[8192]
#define WS_ROWS  73728    // int[8193]
#define WS_ELIST 106512   // int[16384]
#define WS_XRS   172048   // int[16384]  gather row per sorted slot
#define WS_NDS   237584   // int[16384]  output node per sorted slot

// ---------------------------------------------------------------------------
__global__ void prep(const int* __restrict__ pidx, const float* __restrict__ pcoef,
                     _Float16* __restrict__ Cmat, int* __restrict__ hist) {
    const int tid = threadIdx.x;
    if (blockIdx.x < 32) { hist[blockIdx.x * 256 + tid] = 0; return; }
    __shared__ float sC[S_SEG * S_SEG * S_SEG];
    for (int i = tid; i < 4096; i += 256) sC[i] = 0.f;
    __syncthreads();
    for (int p = tid; p < P_PATHS; p += 256) {
        int i = pidx[3 * p + 0];
        int j = pidx[3 * p + 1];
        int k = pidx[3 * p + 2];
        atomicAdd(&sC[(k * S_SEG + i) * S_SEG + j], pcoef[p]);
    }
    __syncthreads();
    for (int i = tid; i < 4096; i += 256) Cmat[i] = (_Float16)sC[i];
}

__global__ void hist_k(const int* __restrict__ idx_out, int* __restrict__ hist) {
    const int e = blockIdx.x * 256 + threadIdx.x;
    atomicAdd(&hist[idx_out[e]], 1);
}

__global__ __launch_bounds__(256) void scan_k(const int* __restrict__ hist,
                                              int* __restrict__ rows,
                                              int* __restrict__ cursor) {
    __shared__ int part[256];
    const int t = threadIdx.x;
    const int base = t * 32;
    int loc[32];
    int s = 0;
#pragma unroll
    for (int i = 0; i < 32; ++i) { loc[i] = s; s += hist[base + i]; }
    part[t] = s;
    __syncthreads();
    for (int off = 1; off < 256; off <<= 1) {
        int v = part[t];
        int u = (t >= off) ? part[t - off] : 0;
        __syncthreads();
        part[t] = v + u;
        __syncthreads();
    }
    const int excl = (t == 0) ? 0 : part[t - 1];
#pragma unroll
    for (int i = 0; i < 32; ++i) {
        int v = excl + loc[i];
        rows[base + i] = v;
        cursor[base + i] = v;
    }
    if (t == 255) rows[N_NODES] = part[255];
}

__global__ void scatter_k(const int* __restrict__ idx_in, const int* __restrict__ idx_out,
                          int* __restrict__ cursor, int* __restrict__ elist,
                          int* __restrict__ xrs, int* __restrict__ nds) {
    const int e = blockIdx.x * 256 + threadIdx.x;
    const int nd = idx_out[e];
    const int pos = atomicAdd(&cursor[nd], 1);
    elist[pos] = e;
    xrs[pos]   = idx_in[e];
    nds[pos]   = nd;
}

// zero the tiles of deg-0 nodes and nodes whose slot range crosses a wave boundary
__global__ __launch_bounds__(256) void zerofill_k(const int* __restrict__ rows,
                                                  float* __restrict__ out) {
    const int n = blockIdx.x * 4 + (threadIdx.x >> 6);
    const int lane = threadIdx.x & 63;
    const int beg = rows[n], end = rows[n + 1];
    const bool need = (beg == end) || ((beg / L_SLOTS) != ((end - 1) / L_SLOTS));
    if (!need) return;
    const float4 z = {0.f, 0.f, 0.f, 0.f};
    float* ob = out + (size_t)n * ROW + lane * 4;
#pragma unroll
    for (int r = 0; r < 4; ++r) *(float4*)(ob + r * 256) = z;
}

// ---------------------------------------------------------------------------
// main: one wave per 8 consecutive sorted edge slots; register double-buffer
// prefetch of next edge's x/y rows; fp16 MFMA; plain store for fully-owned
// nodes, atomicAdd onto zeroed background for wave-boundary nodes.
// ---------------------------------------------------------------------------
__global__ __launch_bounds__(256) void seg_poly_slots(
        const float* __restrict__ x, const float* __restrict__ y,
        const _Float16* __restrict__ Cmat,
        const int* __restrict__ elist, const int* __restrict__ xrs,
        const int* __restrict__ nds, float* __restrict__ out) {
    __shared__ __attribute__((aligned(16))) _Float16 sx_all[4][ROW];
    __shared__ __attribute__((aligned(16))) half2v   sy_all[4][512];

    const int tid  = threadIdx.x;
    const int lane = tid & 63;
    const int wv   = tid >> 6;
    _Float16* sxh = sx_all[wv];
    half2v*   syp = sy_all[wv];

    const int wid = blockIdx.x * 4 + wv;     // 0..2047
    const int s0  = wid * L_SLOTS;

    const int quad = lane >> 4;
    const int m    = lane & 15;
    const int jb2  = (quad & 1) * 4;
    const int ih   = quad >> 1;
    const int jp   = lane >> 3;          // 0..7
    const int cq   = (lane & 7) * 8;     // 8 cols per lane

    // per-slot metadata (wave-uniform)
    int e_[L_SLOTS], xr_[L_SLOTS], nd_[L_SLOTS];
    {
        int4 a = *(const int4*)(elist + s0); int4 b = *(const int4*)(elist + s0 + 4);
        e_[0]=a.x; e_[1]=a.y; e_[2]=a.z; e_[3]=a.w; e_[4]=b.x; e_[5]=b.y; e_[6]=b.z; e_[7]=b.w;
        a = *(const int4*)(xrs + s0); b = *(const int4*)(xrs + s0 + 4);
        xr_[0]=a.x; xr_[1]=a.y; xr_[2]=a.z; xr_[3]=a.w; xr_[4]=b.x; xr_[5]=b.y; xr_[6]=b.z; xr_[7]=b.w;
        a = *(const int4*)(nds + s0); b = *(const int4*)(nds + s0 + 4);
        nd_[0]=a.x; nd_[1]=a.y; nd_[2]=a.z; nd_[3]=a.w; nd_[4]=b.x; nd_[5]=b.y; nd_[6]=b.z; nd_[7]=b.w;
    }
    const bool prev_same = (s0 > 0)                  && (nds[s0 - 1]       == nd_[0]);
    const bool next_same = (s0 + L_SLOTS < E_EDGES)  && (nds[s0 + L_SLOTS] == nd_[L_SLOTS - 1]);

    // A fragments (constant): afrag[kk][jr] = Cmat[m][kk*32 + quad*8 + jr]
    f16x8 afrag[8];
    {
        const _Float16* basep = Cmat + m * 256 + quad * 8;
#pragma unroll
        for (int kk = 0; kk < 8; ++kk) afrag[kk] = *(const f16x8*)(basep + kk * 32);
    }

    float4 xbuf[2][4], ybuf[2][4];
    auto issue = [&](int t, int b) {
        const float* xp = x + (size_t)xr_[t] * ROW;
        const float* yp = y + (size_t)e_[t] * ROW;
#pragma unroll
        for (int k4 = 0; k4 < 4; ++k4)
            xbuf[b][k4] = *(const float4*)(xp + k4 * 256 + lane * 4);
        ybuf[b][0] = *(const float4*)(yp + (2 * jp)     * EXT + cq);
        ybuf[b][1] = *(const float4*)(yp + (2 * jp)     * EXT + cq + 4);
        ybuf[b][2] = *(const float4*)(yp + (2 * jp + 1) * EXT + cq);
        ybuf[b][3] = *(const float4*)(yp + (2 * jp + 1) * EXT + cq + 4);
    };
    issue(0, 0);

    f32x4 acc[4];
#pragma unroll
    for (int ct = 0; ct < 4; ++ct) acc[ct] = f32x4{0.f, 0.f, 0.f, 0.f};
    int segStart = 0;

#pragma unroll
    for (int t = 0; t < L_SLOTS; ++t) {
        const int b = t & 1;
        if (t + 1 < L_SLOTS) issue(t + 1, b ^ 1);   // prefetch next edge

        // stage current edge regs -> f16 LDS (wave-private, no barriers)
#pragma unroll
        for (int k4 = 0; k4 < 4; ++k4) {
            const float4 v = xbuf[b][k4];
            *(f16x4*)(sxh + k4 * 256 + lane * 4) =
                f16x4{(_Float16)v.x, (_Float16)v.y, (_Float16)v.z, (_Float16)v.w};
        }
        {
            const float4 a0 = ybuf[b][0], a1 = ybuf[b][1];
            const float4 c0 = ybuf[b][2], c1 = ybuf[b][3];
            *(f16x8*)(syp + jp * 64 + cq) =
                f16x8{(_Float16)a0.x, (_Float16)c0.x, (_Float16)a0.y, (_Float16)c0.y,
                      (_Float16)a0.z, (_Float16)c0.z, (_Float16)a0.w, (_Float16)c0.w};
            *(f16x8*)(syp + jp * 64 + cq + 4) =
                f16x8{(_Float16)a1.x, (_Float16)c1.x, (_Float16)a1.y, (_Float16)c1.y,
                      (_Float16)a1.z, (_Float16)c1.z, (_Float16)a1.w, (_Float16)c1.w};
        }

        // compute: 4 col-tiles x 8 K-steps of mfma_f32_16x16x32_f16
#pragma unroll
        for (int ct = 0; ct < 4; ++ct) {
            const int c = ct * 16 + m;
            half2v ypk[4];
#pragma unroll
            for (int r = 0; r < 4; ++r) ypk[r] = syp[(jb2 + r) * 64 + c];
#pragma unroll
            for (int kk = 0; kk < 8; ++kk) {
                const _Float16 xh = sxh[(2 * kk + ih) * EXT + c];
                const half2v hx = {xh, xh};
                const half2v b0 = hx * ypk[0];
                const half2v b1 = hx * ypk[1];
                const half2v b2 = hx * ypk[2];
                const half2v b3 = hx * ypk[3];
                const f16x8 bfrag = {b0[0], b0[1], b1[0], b1[1],
                                     b2[0], b2[1], b3[0], b3[1]};
                acc[ct] = __builtin_amdgcn_mfma_f32_16x16x32_f16(
                              afrag[kk], bfrag, acc[ct], 0, 0, 0);
            }
        }

        // flush at node boundary
        const bool last = (t == L_SLOTS - 1);
        if (last || nd_[t + 1] != nd_[t]) {
            const bool shared = (segStart == 0 && prev_same) || (last && next_same);
            float* ob = out + (size_t)nd_[t] * ROW;
            if (shared) {
#pragma unroll
                for (int ct = 0; ct < 4; ++ct)
#pragma unroll
                    for (int r = 0; r < 4; ++r)
                        atomicAdd(ob + (quad * 4 + r) * EXT + ct * 16 + m, acc[ct][r]);
            } else {
#pragma unroll
                for (int ct = 0; ct < 4; ++ct)
#pragma unroll
                    for (int r = 0; r < 4; ++r)
                        ob[(quad * 4 + r) * EXT + ct * 16 + m] = acc[ct][r];
            }
#pragma unroll
            for (int ct = 0; ct < 4; ++ct) acc[ct] = f32x4{0.f, 0.f, 0.f, 0.f};
            segStart = t + 1;
        }
    }
}

extern "C" void kernel_launch(void* const* d_in, const int* in_sizes, int n_in,
                              void* d_out, int out_size, void* d_ws, size_t ws_size,
                              hipStream_t stream) {
    const float* x       = (const float*)d_in[0];
    const float* y       = (const float*)d_in[1];
    const int*   idx_in  = (const int*)d_in[2];
    const int*   idx_out = (const int*)d_in[3];
    const int*   pidx    = (const int*)d_in[4];
    const float* pcoef   = (const float*)d_in[5];
    float* out           = (float*)d_out;

    char* ws = (char*)d_ws;
    _Float16* Cmat = (_Float16*)(ws + WS_CMAT);
    int* hist      = (int*)(ws + WS_HIST);
    int* cursor    = (int*)(ws + WS_CURS);
    int* rows      = (int*)(ws + WS_ROWS);
    int* elist     = (int*)(ws + WS_ELIST);
    int* xrs       = (int*)(ws + WS_XRS);
    int* nds       = (int*)(ws + WS_NDS);

    prep<<<33, 256, 0, stream>>>(pidx, pcoef, Cmat, hist);
    hist_k<<<E_EDGES / 256, 256, 0, stream>>>(idx_out, hist);
    scan_k<<<1, 256, 0, stream>>>(hist, rows, cursor);
    scatter_k<<<E_EDGES / 256, 256, 0, stream>>>(idx_in, idx_out, cursor, elist, xrs, nds);
    zerofill_k<<<N_NODES / 4, 256, 0, stream>>>(rows, out);
    seg_poly_slots<<<NBLK, 256, 0, stream>>>(x, y, Cmat, elist, xrs, nds, out);
}